// Round 1
// baseline (570.112 us; speedup 1.0000x reference)
//
#include <hip/hip_runtime.h>
#include <math.h>

#define B_SZ    16384
#define NNZ_PER 32
#define NNZ     (B_SZ * NNZ_PER)
#define FT_OUT  512
#define F_BIG   49152
#define F_SMALL 768
#define MODV    640

// ---------------------------------------------------------------------------
// ws layout (floats):
//   Wt      : F_BIG * FT_OUT           (transposed big weight, [c][o])
//   Wfft_t  : MODV * FT_OUT            (transposed small weight cols 0..639)
//   H       : 2 * MODV * MODV          (weighted histograms, stm / nstm)
//   fft_acc : 2 * MODV * FT_OUT        (H @ Wfft^T per side)
// total ~103 MB
// ---------------------------------------------------------------------------

__global__ void transpose_wft(const float* __restrict__ W, float* __restrict__ Wt) {
    __shared__ float tile[32][33];
    int c0 = blockIdx.x * 32;
    int o0 = blockIdx.y * 32;
    int tx = threadIdx.x;   // 0..31
    int ty = threadIdx.y;   // 0..7
#pragma unroll
    for (int j = 0; j < 32; j += 8)
        tile[ty + j][tx] = W[(size_t)(o0 + ty + j) * F_BIG + (c0 + tx)];
    __syncthreads();
#pragma unroll
    for (int j = 0; j < 32; j += 8)
        Wt[(size_t)(c0 + ty + j) * FT_OUT + (o0 + tx)] = tile[tx][ty + j];
}

__global__ void transpose_wfft(const float* __restrict__ W, float* __restrict__ Wt) {
    __shared__ float tile[32][33];
    int c0 = blockIdx.x * 32;   // cc in [0,640)
    int o0 = blockIdx.y * 32;   // o in [0,512)
    int tx = threadIdx.x;
    int ty = threadIdx.y;
#pragma unroll
    for (int j = 0; j < 32; j += 8)
        tile[ty + j][tx] = W[(size_t)(o0 + ty + j) * F_SMALL + (c0 + tx)];
    __syncthreads();
#pragma unroll
    for (int j = 0; j < 32; j += 8)
        Wt[(size_t)(c0 + ty + j) * FT_OUT + (o0 + tx)] = tile[tx][ty + j];
}

__global__ void hist_kernel(const int* __restrict__ stm, const int* __restrict__ nstm,
                            const float* __restrict__ vals, float* __restrict__ H) {
    int i = blockIdx.x * 256 + threadIdx.x;
    if (i < NNZ) {
        int r = stm[i] % MODV;           // rows at offset 0
        int c = stm[NNZ + i] % MODV;     // cols at offset NNZ
        atomicAdd(&H[r * MODV + c], vals[i]);
    } else if (i < 2 * NNZ) {
        int j = i - NNZ;
        int r = nstm[j] % MODV;
        int c = nstm[NNZ + j] % MODV;
        atomicAdd(&H[MODV * MODV + r * MODV + c], vals[j]);
    }
}

// fft_acc[side][s][o] = sum_cc H[side][s][cc] * Wfft_t[cc][o]
__global__ __launch_bounds__(512)
void fft_gemm(const float* __restrict__ H, const float* __restrict__ Wfft_t,
              float* __restrict__ acc) {
    __shared__ float hs[8][MODV];
    int o = threadIdx.x;                 // 0..511
    int b = blockIdx.x;                  // 0..159
    int side = b / (MODV / 8);
    int s0 = (b % (MODV / 8)) * 8;
    const float* Hs = H + (size_t)side * MODV * MODV;
    for (int t = threadIdx.x; t < 8 * MODV; t += 512)
        hs[t / MODV][t % MODV] = Hs[(size_t)(s0 + t / MODV) * MODV + (t % MODV)];
    __syncthreads();
    float a[8] = {0, 0, 0, 0, 0, 0, 0, 0};
    for (int cc = 0; cc < MODV; cc++) {
        float w = Wfft_t[(size_t)cc * FT_OUT + o];
#pragma unroll
        for (int j = 0; j < 8; j++) a[j] += hs[j][cc] * w;
    }
#pragma unroll
    for (int j = 0; j < 8; j++)
        acc[(size_t)side * MODV * FT_OUT + (size_t)(s0 + j) * FT_OUT + o] = a[j];
}

__device__ __forceinline__ float clip01(float x) {
    return fminf(fmaxf(x, 0.0f), 1.0f);
}

// one block per row; 128 threads, each owns 4 output features (float4)
__global__ __launch_bounds__(128)
void main_kernel(const int* __restrict__ stm, const int* __restrict__ nstm,
                 const float* __restrict__ vals,
                 const float* __restrict__ Wt,
                 const float* __restrict__ b_ft, const float* __restrict__ b_fft,
                 const float* __restrict__ fft_acc,
                 const float* __restrict__ W_out, const float* __restrict__ b_out,
                 float* __restrict__ out) {
    int row = blockIdx.x;
    int tid = threadIdx.x;

    __shared__ int   s_c[2][NNZ_PER];
    __shared__ float s_v[NNZ_PER];
    if (tid < NNZ_PER) {
        s_c[0][tid] = stm[NNZ + row * NNZ_PER + tid];
        s_v[tid]    = vals[row * NNZ_PER + tid];
    } else if (tid < 2 * NNZ_PER) {
        int k = tid - NNZ_PER;
        s_c[1][k] = nstm[NNZ + row * NNZ_PER + k];
    }
    __syncthreads();

    float a0x = 0, a0y = 0, a0z = 0, a0w = 0;   // stm accumulator
    float a1x = 0, a1y = 0, a1z = 0, a1w = 0;   // nstm accumulator
#pragma unroll 4
    for (int k = 0; k < NNZ_PER; k++) {
        float v = s_v[k];
        const float4* p0 = (const float4*)(Wt + (size_t)s_c[0][k] * FT_OUT);
        const float4* p1 = (const float4*)(Wt + (size_t)s_c[1][k] * FT_OUT);
        float4 w0 = p0[tid];
        float4 w1 = p1[tid];
        a0x += v * w0.x; a0y += v * w0.y; a0z += v * w0.z; a0w += v * w0.w;
        a1x += v * w1.x; a1y += v * w1.y; a1z += v * w1.z; a1w += v * w1.w;
    }

    float4 bft  = ((const float4*)b_ft)[tid];
    float4 bfft = ((const float4*)b_fft)[tid];
    float4 f0 = {0, 0, 0, 0}, f1 = {0, 0, 0, 0};
    if (row < MODV) {
        f0 = ((const float4*)(fft_acc + (size_t)row * FT_OUT))[tid];
        f1 = ((const float4*)(fft_acc + (size_t)(MODV + row) * FT_OUT))[tid];
    }

    float h0x = clip01(a0x + bft.x + bfft.x + f0.x);
    float h0y = clip01(a0y + bft.y + bfft.y + f0.y);
    float h0z = clip01(a0z + bft.z + bfft.z + f0.z);
    float h0w = clip01(a0w + bft.w + bfft.w + f0.w);
    float h1x = clip01(a1x + bft.x + bfft.x + f1.x);
    float h1y = clip01(a1y + bft.y + bfft.y + f1.y);
    float h1z = clip01(a1z + bft.z + bfft.z + f1.z);
    float h1w = clip01(a1w + bft.w + bfft.w + f1.w);

    float4 wo0 = ((const float4*)W_out)[tid];          // stm half: cols 0..511
    float4 wo1 = ((const float4*)W_out)[128 + tid];    // nstm half: cols 512..1023

    float dot = h0x * wo0.x + h0y * wo0.y + h0z * wo0.z + h0w * wo0.w
              + h1x * wo1.x + h1y * wo1.y + h1z * wo1.z + h1w * wo1.w;

#pragma unroll
    for (int off = 32; off > 0; off >>= 1)
        dot += __shfl_down(dot, off, 64);

    __shared__ float partial[2];
    if ((tid & 63) == 0) partial[tid >> 6] = dot;
    __syncthreads();
    if (tid == 0) {
        float z = partial[0] + partial[1] + b_out[0];
        out[row] = 1.0f / (1.0f + expf(-z));
    }
}

extern "C" void kernel_launch(void* const* d_in, const int* in_sizes, int n_in,
                              void* d_out, int out_size, void* d_ws, size_t ws_size,
                              hipStream_t stream) {
    const int*   stm   = (const int*)d_in[0];
    const int*   nstm  = (const int*)d_in[1];
    const float* vals  = (const float*)d_in[2];
    // d_in[3]: size scalar (compile-time B_SZ)
    const float* W_ft  = (const float*)d_in[4];
    const float* b_ft  = (const float*)d_in[5];
    const float* W_fft = (const float*)d_in[6];
    const float* b_fft = (const float*)d_in[7];
    const float* W_out = (const float*)d_in[8];
    const float* b_out = (const float*)d_in[9];
    float* out = (float*)d_out;

    float* ws      = (float*)d_ws;
    float* Wt      = ws;                                      // F_BIG*FT_OUT
    float* Wfft_t  = Wt + (size_t)F_BIG * FT_OUT;             // MODV*FT_OUT
    float* H       = Wfft_t + (size_t)MODV * FT_OUT;          // 2*MODV*MODV
    float* fft_acc = H + (size_t)2 * MODV * MODV;             // 2*MODV*FT_OUT

    hipMemsetAsync(H, 0, (size_t)2 * MODV * MODV * sizeof(float), stream);

    transpose_wft<<<dim3(F_BIG / 32, FT_OUT / 32), dim3(32, 8), 0, stream>>>(W_ft, Wt);
    transpose_wfft<<<dim3(MODV / 32, FT_OUT / 32), dim3(32, 8), 0, stream>>>(W_fft, Wfft_t);
    hist_kernel<<<(2 * NNZ + 255) / 256, 256, 0, stream>>>(stm, nstm, vals, H);
    fft_gemm<<<2 * (MODV / 8), 512, 0, stream>>>(H, Wfft_t, fft_acc);
    main_kernel<<<B_SZ, 128, 0, stream>>>(stm, nstm, vals, Wt, b_ft, b_fft, fft_acc,
                                          W_out, b_out, out);
}

// Round 2
// 392.990 us; speedup vs baseline: 1.4507x; 1.4507x over previous
//
#include <hip/hip_runtime.h>
#include <math.h>

#define B_SZ    16384
#define NNZ_PER 32
#define NNZ     (B_SZ * NNZ_PER)
#define FT_OUT  512
#define F_BIG   49152
#define F_SMALL 768
#define MODV    640

// ---------------------------------------------------------------------------
// ws layout:
//   Wt_bf   : F_BIG * FT_OUT ushort   (transposed big weight, bf16, [c][o]) 48 MB
//   Wfft_t  : MODV * FT_OUT float     (transposed small weight cols 0..639)
//   H       : 2 * MODV * MODV float   (weighted histograms, stm / nstm)
//   fft_acc : 2 * MODV * FT_OUT float (H @ Wfft^T per side, atomically built)
// ---------------------------------------------------------------------------

__device__ __forceinline__ unsigned short f32_to_bf16_rne(float f) {
    union { float f; unsigned int u; } v; v.f = f;
    unsigned int u = v.u;
    return (unsigned short)((u + 0x7fffu + ((u >> 16) & 1u)) >> 16);
}

__device__ __forceinline__ void unpack_bf16x2(unsigned int u, float& lo, float& hi) {
    union { unsigned int i; float f; } a, b;
    a.i = u << 16;            // even element
    b.i = u & 0xffff0000u;    // odd element
    lo = a.f; hi = b.f;
}

__global__ void transpose_wft(const float* __restrict__ W, unsigned short* __restrict__ Wt) {
    __shared__ float tile[32][33];
    int c0 = blockIdx.x * 32;
    int o0 = blockIdx.y * 32;
    int tx = threadIdx.x;   // 0..31
    int ty = threadIdx.y;   // 0..7
#pragma unroll
    for (int j = 0; j < 32; j += 8)
        tile[ty + j][tx] = W[(size_t)(o0 + ty + j) * F_BIG + (c0 + tx)];
    __syncthreads();
#pragma unroll
    for (int j = 0; j < 32; j += 8)
        Wt[(size_t)(c0 + ty + j) * FT_OUT + (o0 + tx)] = f32_to_bf16_rne(tile[tx][ty + j]);
}

__global__ void transpose_wfft(const float* __restrict__ W, float* __restrict__ Wt) {
    __shared__ float tile[32][33];
    int c0 = blockIdx.x * 32;   // cc in [0,640)
    int o0 = blockIdx.y * 32;   // o in [0,512)
    int tx = threadIdx.x;
    int ty = threadIdx.y;
#pragma unroll
    for (int j = 0; j < 32; j += 8)
        tile[ty + j][tx] = W[(size_t)(o0 + ty + j) * F_SMALL + (c0 + tx)];
    __syncthreads();
#pragma unroll
    for (int j = 0; j < 32; j += 8)
        Wt[(size_t)(c0 + ty + j) * FT_OUT + (o0 + tx)] = tile[tx][ty + j];
}

__global__ void hist_kernel(const int* __restrict__ stm, const int* __restrict__ nstm,
                            const float* __restrict__ vals, float* __restrict__ H) {
    int i = blockIdx.x * 256 + threadIdx.x;
    if (i < NNZ) {
        int r = stm[i] % MODV;           // rows at offset 0
        int c = stm[NNZ + i] % MODV;     // cols at offset NNZ
        atomicAdd(&H[r * MODV + c], vals[i]);
    } else if (i < 2 * NNZ) {
        int j = i - NNZ;
        int r = nstm[j] % MODV;
        int c = nstm[NNZ + j] % MODV;
        atomicAdd(&H[MODV * MODV + r * MODV + c], vals[j]);
    }
}

// fft_acc[side][s][o] += sum_{cc in chunk} H[side][s][cc] * Wfft_t[cc][o]
// grid = 2 sides * 80 s-tiles * 4 cc-chunks = 640 blocks, 512 threads
#define CC_CHUNK 160
__global__ __launch_bounds__(512)
void fft_gemm(const float* __restrict__ H, const float* __restrict__ Wfft_t,
              float* __restrict__ acc) {
    __shared__ float hs[8][CC_CHUNK];
    int o = threadIdx.x;                 // 0..511
    int b = blockIdx.x;
    int side  = b / 320;
    int rem   = b % 320;
    int s0    = (rem / 4) * 8;
    int cc0   = (rem % 4) * CC_CHUNK;
    const float* Hs = H + (size_t)side * MODV * MODV;
    for (int t = threadIdx.x; t < 8 * CC_CHUNK; t += 512) {
        int j = t / CC_CHUNK, cc = t % CC_CHUNK;
        hs[j][cc] = Hs[(size_t)(s0 + j) * MODV + (cc0 + cc)];
    }
    __syncthreads();
    float a[8] = {0, 0, 0, 0, 0, 0, 0, 0};
    for (int cc = 0; cc < CC_CHUNK; cc++) {
        float w = Wfft_t[(size_t)(cc0 + cc) * FT_OUT + o];
#pragma unroll
        for (int j = 0; j < 8; j++) a[j] += hs[j][cc] * w;
    }
    float* dst = acc + (size_t)side * MODV * FT_OUT + (size_t)s0 * FT_OUT + o;
#pragma unroll
    for (int j = 0; j < 8; j++)
        atomicAdd(dst + (size_t)j * FT_OUT, a[j]);
}

__device__ __forceinline__ float clip01(float x) {
    return fminf(fmaxf(x, 0.0f), 1.0f);
}

// one block (= one wave, 64 threads) per row; each lane owns 8 output features
__global__ __launch_bounds__(64)
void main_kernel(const int* __restrict__ stm, const int* __restrict__ nstm,
                 const float* __restrict__ vals,
                 const unsigned short* __restrict__ Wt,
                 const float* __restrict__ b_ft, const float* __restrict__ b_fft,
                 const float* __restrict__ fft_acc,
                 const float* __restrict__ W_out, const float* __restrict__ b_out,
                 float* __restrict__ out) {
    int row = blockIdx.x;
    int tid = threadIdx.x;   // 0..63

    __shared__ int   s_c[2][NNZ_PER];
    __shared__ float s_v[NNZ_PER];
    if (tid < NNZ_PER) {
        s_c[0][tid] = stm[NNZ + row * NNZ_PER + tid];
        s_v[tid]    = vals[row * NNZ_PER + tid];
    } else {
        int k = tid - NNZ_PER;
        s_c[1][k] = nstm[NNZ + row * NNZ_PER + k];
    }
    __syncthreads();

    float a0[8] = {0, 0, 0, 0, 0, 0, 0, 0};   // stm, features o_base..o_base+7
    float a1[8] = {0, 0, 0, 0, 0, 0, 0, 0};   // nstm

#pragma unroll 4
    for (int k = 0; k < NNZ_PER; k++) {
        float v = s_v[k];
        const uint4* p0 = (const uint4*)(Wt + (size_t)s_c[0][k] * FT_OUT);
        const uint4* p1 = (const uint4*)(Wt + (size_t)s_c[1][k] * FT_OUT);
        uint4 w0 = p0[tid];
        uint4 w1 = p1[tid];
        float e0, e1;
        unpack_bf16x2(w0.x, e0, e1); a0[0] += v * e0; a0[1] += v * e1;
        unpack_bf16x2(w0.y, e0, e1); a0[2] += v * e0; a0[3] += v * e1;
        unpack_bf16x2(w0.z, e0, e1); a0[4] += v * e0; a0[5] += v * e1;
        unpack_bf16x2(w0.w, e0, e1); a0[6] += v * e0; a0[7] += v * e1;
        unpack_bf16x2(w1.x, e0, e1); a1[0] += v * e0; a1[1] += v * e1;
        unpack_bf16x2(w1.y, e0, e1); a1[2] += v * e0; a1[3] += v * e1;
        unpack_bf16x2(w1.z, e0, e1); a1[4] += v * e0; a1[5] += v * e1;
        unpack_bf16x2(w1.w, e0, e1); a1[6] += v * e0; a1[7] += v * e1;
    }

    int ob = tid * 8;
    float4 bft0  = ((const float4*)(b_ft + ob))[0];
    float4 bft1  = ((const float4*)(b_ft + ob))[1];
    float4 bff0  = ((const float4*)(b_fft + ob))[0];
    float4 bff1  = ((const float4*)(b_fft + ob))[1];
    float4 f00 = {0,0,0,0}, f01 = {0,0,0,0}, f10 = {0,0,0,0}, f11 = {0,0,0,0};
    if (row < MODV) {
        const float* fa0 = fft_acc + (size_t)row * FT_OUT + ob;
        const float* fa1 = fft_acc + (size_t)(MODV + row) * FT_OUT + ob;
        f00 = ((const float4*)fa0)[0]; f01 = ((const float4*)fa0)[1];
        f10 = ((const float4*)fa1)[0]; f11 = ((const float4*)fa1)[1];
    }

    float h0[8], h1[8];
    h0[0] = clip01(a0[0] + bft0.x + bff0.x + f00.x);
    h0[1] = clip01(a0[1] + bft0.y + bff0.y + f00.y);
    h0[2] = clip01(a0[2] + bft0.z + bff0.z + f00.z);
    h0[3] = clip01(a0[3] + bft0.w + bff0.w + f00.w);
    h0[4] = clip01(a0[4] + bft1.x + bff1.x + f01.x);
    h0[5] = clip01(a0[5] + bft1.y + bff1.y + f01.y);
    h0[6] = clip01(a0[6] + bft1.z + bff1.z + f01.z);
    h0[7] = clip01(a0[7] + bft1.w + bff1.w + f01.w);
    h1[0] = clip01(a1[0] + bft0.x + bff0.x + f10.x);
    h1[1] = clip01(a1[1] + bft0.y + bff0.y + f10.y);
    h1[2] = clip01(a1[2] + bft0.z + bff0.z + f10.z);
    h1[3] = clip01(a1[3] + bft0.w + bff0.w + f10.w);
    h1[4] = clip01(a1[4] + bft1.x + bff1.x + f11.x);
    h1[5] = clip01(a1[5] + bft1.y + bff1.y + f11.y);
    h1[6] = clip01(a1[6] + bft1.z + bff1.z + f11.z);
    h1[7] = clip01(a1[7] + bft1.w + bff1.w + f11.w);

    float4 wo00 = ((const float4*)(W_out + ob))[0];
    float4 wo01 = ((const float4*)(W_out + ob))[1];
    float4 wo10 = ((const float4*)(W_out + FT_OUT + ob))[0];
    float4 wo11 = ((const float4*)(W_out + FT_OUT + ob))[1];

    float dot = h0[0] * wo00.x + h0[1] * wo00.y + h0[2] * wo00.z + h0[3] * wo00.w
              + h0[4] * wo01.x + h0[5] * wo01.y + h0[6] * wo01.z + h0[7] * wo01.w
              + h1[0] * wo10.x + h1[1] * wo10.y + h1[2] * wo10.z + h1[3] * wo10.w
              + h1[4] * wo11.x + h1[5] * wo11.y + h1[6] * wo11.z + h1[7] * wo11.w;

#pragma unroll
    for (int off = 32; off > 0; off >>= 1)
        dot += __shfl_down(dot, off, 64);

    if (tid == 0)
        out[row] = 1.0f / (1.0f + expf(-(dot + b_out[0])));
}

extern "C" void kernel_launch(void* const* d_in, const int* in_sizes, int n_in,
                              void* d_out, int out_size, void* d_ws, size_t ws_size,
                              hipStream_t stream) {
    const int*   stm   = (const int*)d_in[0];
    const int*   nstm  = (const int*)d_in[1];
    const float* vals  = (const float*)d_in[2];
    // d_in[3]: size scalar (compile-time B_SZ)
    const float* W_ft  = (const float*)d_in[4];
    const float* b_ft  = (const float*)d_in[5];
    const float* W_fft = (const float*)d_in[6];
    const float* b_fft = (const float*)d_in[7];
    const float* W_out = (const float*)d_in[8];
    const float* b_out = (const float*)d_in[9];
    float* out = (float*)d_out;

    unsigned short* Wt_bf = (unsigned short*)d_ws;                  // F_BIG*FT_OUT ushort
    float* Wfft_t  = (float*)(Wt_bf + (size_t)F_BIG * FT_OUT);      // MODV*FT_OUT
    float* H       = Wfft_t + (size_t)MODV * FT_OUT;                // 2*MODV*MODV
    float* fft_acc = H + (size_t)2 * MODV * MODV;                   // 2*MODV*FT_OUT

    hipMemsetAsync(H, 0, (size_t)2 * MODV * MODV * sizeof(float), stream);
    hipMemsetAsync(fft_acc, 0, (size_t)2 * MODV * FT_OUT * sizeof(float), stream);

    transpose_wft<<<dim3(F_BIG / 32, FT_OUT / 32), dim3(32, 8), 0, stream>>>(W_ft, Wt_bf);
    transpose_wfft<<<dim3(MODV / 32, FT_OUT / 32), dim3(32, 8), 0, stream>>>(W_fft, Wfft_t);
    hist_kernel<<<(2 * NNZ + 255) / 256, 256, 0, stream>>>(stm, nstm, vals, H);
    fft_gemm<<<640, 512, 0, stream>>>(H, Wfft_t, fft_acc);
    main_kernel<<<B_SZ, 64, 0, stream>>>(stm, nstm, vals, Wt_bf, b_ft, b_fft, fft_acc,
                                         W_out, b_out, out);
}

// Round 3
// 389.801 us; speedup vs baseline: 1.4626x; 1.0082x over previous
//
#include <hip/hip_runtime.h>
#include <math.h>

#define B_SZ    16384
#define NNZ_PER 32
#define NNZ     (B_SZ * NNZ_PER)
#define FT_OUT  512
#define F_BIG   49152
#define F_SMALL 768
#define MODV    640

// prep grid partition
#define TP_A     6144              // W_ft 64x64 tiles: 8 ot x 768 ct
#define TP_B     80                // W_fft 64x64 tiles: 8 ot x 10 ct
#define HISTB    512
#define PREP_GRID (TP_A + TP_B + HISTB)

// ---------------------------------------------------------------------------
// ws layout:
//   Wt_bf    : F_BIG*FT_OUT ushort      48 MB  transposed big weight, bf16
//   Wfft_t   : MODV*FT_OUT float        1.3 MB transposed small weight (fp32)
//   H        : 2*MODV*MODV float        3.3 MB weighted histograms
//   fft_part : 4*2*MODV*FT_OUT float   10.5 MB partial H @ Wfft^T (4 cc-chunks)
// ---------------------------------------------------------------------------

__device__ __forceinline__ unsigned short f32_to_bf16_rne(float f) {
    union { float f; unsigned int u; } v; v.f = f;
    unsigned int u = v.u;
    return (unsigned short)((u + 0x7fffu + ((u >> 16) & 1u)) >> 16);
}

__device__ __forceinline__ void unpack_bf16x2(unsigned int u, float& lo, float& hi) {
    union { unsigned int i; float f; } a, b;
    a.i = u << 16;            // even element
    b.i = u & 0xffff0000u;    // odd element
    lo = a.f; hi = b.f;
}

__device__ __forceinline__ float clip01(float x) {
    return fminf(fmaxf(x, 0.0f), 1.0f);
}

// One kernel for all prologue work: transpose+bf16-quantize W_ft, transpose
// W_fft (fp32), and the mod-640 weighted histogram.
__global__ __launch_bounds__(256)
void prep_kernel(const float* __restrict__ W_ft, const float* __restrict__ W_fft,
                 const int* __restrict__ stm, const int* __restrict__ nstm,
                 const float* __restrict__ vals,
                 unsigned short* __restrict__ Wt, float* __restrict__ Wfft_t,
                 float* __restrict__ H) {
    int b = blockIdx.x;
    int tid = threadIdx.x;
    if (b < TP_A + TP_B) {
        __shared__ float tile[64][65];
        const bool isA = b < TP_A;
        int b2 = isA ? b : b - TP_A;
        int nct = isA ? (F_BIG / 64) : (MODV / 64);
        int rowlen = isA ? F_BIG : F_SMALL;
        const float* src = isA ? W_ft : W_fft;
        int ot = b2 / nct, ct = b2 % nct;
        int c0 = ct * 64, o0 = ot * 64;
        int rr = tid >> 4, c4 = (tid & 15) * 4;
#pragma unroll
        for (int it = 0; it < 4; it++) {
            int oo = rr + it * 16;
            float4 f = *(const float4*)(src + (size_t)(o0 + oo) * rowlen + c0 + c4);
            tile[oo][c4 + 0] = f.x; tile[oo][c4 + 1] = f.y;
            tile[oo][c4 + 2] = f.z; tile[oo][c4 + 3] = f.w;
        }
        __syncthreads();
        if (isA) {
            // 64 c-rows x 64 bf16 = 8 uint4 lanes per row
#pragma unroll
            for (int it = 0; it < 2; it++) {
                int idx = tid + it * 256;
                int cc = idx >> 3, g = idx & 7;
                unsigned int pk[4];
#pragma unroll
                for (int q = 0; q < 4; q++) {
                    unsigned int lo = f32_to_bf16_rne(tile[g * 8 + 2 * q][cc]);
                    unsigned int hi = f32_to_bf16_rne(tile[g * 8 + 2 * q + 1][cc]);
                    pk[q] = lo | (hi << 16);
                }
                *(uint4*)(Wt + (size_t)(c0 + cc) * FT_OUT + o0 + g * 8) =
                    make_uint4(pk[0], pk[1], pk[2], pk[3]);
            }
        } else {
            // 64 c-rows x 64 fp32 = 16 float4 lanes per row
#pragma unroll
            for (int it = 0; it < 4; it++) {
                int idx = tid + it * 256;
                int cc = idx >> 4, g = idx & 15;
                float4 v = make_float4(tile[g * 4 + 0][cc], tile[g * 4 + 1][cc],
                                       tile[g * 4 + 2][cc], tile[g * 4 + 3][cc]);
                *(float4*)(Wfft_t + (size_t)(c0 + cc) * FT_OUT + o0 + g * 4) = v;
            }
        }
    } else {
        int i0 = (b - TP_A - TP_B) * 256 + tid;
        for (int e = i0; e < 2 * NNZ; e += HISTB * 256) {
            int side = (e >= NNZ) ? 1 : 0;
            int j = e - side * NNZ;
            const int* arr = side ? nstm : stm;
            int r = arr[j] % MODV;          // row indices at offset 0
            int c = arr[NNZ + j] % MODV;    // col indices at offset NNZ
            atomicAdd(&H[(size_t)side * MODV * MODV + r * MODV + c], vals[j]);
        }
    }
}

// part[ck][side][s][o] = sum_{cc in chunk ck} H[side][s][cc] * Wfft_t[cc][o]
// grid = 2 sides x 80 s-tiles x 4 cc-chunks = 640 blocks, no atomics
#define CC_CHUNK 160
__global__ __launch_bounds__(512)
void fft_gemm(const float* __restrict__ H, const float* __restrict__ Wfft_t,
              float* __restrict__ part) {
    __shared__ float hs[8][CC_CHUNK];
    int o = threadIdx.x;                 // 0..511
    int b = blockIdx.x;
    int side = b / 320;
    int rem  = b % 320;
    int s0   = (rem >> 2) * 8;
    int ck   = rem & 3;
    int cc0  = ck * CC_CHUNK;
    const float* Hs = H + (size_t)side * MODV * MODV;
    for (int t = threadIdx.x; t < 8 * CC_CHUNK; t += 512) {
        int j = t / CC_CHUNK, cc = t - j * CC_CHUNK;
        hs[j][cc] = Hs[(size_t)(s0 + j) * MODV + cc0 + cc];
    }
    __syncthreads();
    float a[8] = {0, 0, 0, 0, 0, 0, 0, 0};
    for (int cc = 0; cc < CC_CHUNK; cc++) {
        float wv = Wfft_t[(size_t)(cc0 + cc) * FT_OUT + o];
#pragma unroll
        for (int j = 0; j < 8; j++) a[j] += hs[j][cc] * wv;
    }
    float* dst = part + ((size_t)(ck * 2 + side) * MODV + s0) * FT_OUT + o;
#pragma unroll
    for (int j = 0; j < 8; j++) dst[(size_t)j * FT_OUT] = a[j];
}

// 4 rows per 256-thread block (one wave per row) -> 32 waves/CU possible.
__global__ __launch_bounds__(256, 8)
void main_kernel(const int* __restrict__ stm, const int* __restrict__ nstm,
                 const float* __restrict__ vals,
                 const unsigned short* __restrict__ Wt,
                 const float* __restrict__ b_ft, const float* __restrict__ b_fft,
                 const float* __restrict__ fft_part,
                 const float* __restrict__ W_out, const float* __restrict__ b_out,
                 float* __restrict__ out) {
    int w    = threadIdx.x >> 6;           // wave 0..3
    int lane = threadIdx.x & 63;
    int row  = blockIdx.x * 4 + w;

    __shared__ int   s_c[4][2][NNZ_PER];
    __shared__ float s_v[4][NNZ_PER];
    if (lane < NNZ_PER) {
        s_c[w][0][lane] = stm[NNZ + row * NNZ_PER + lane];
        s_v[w][lane]    = vals[row * NNZ_PER + lane];
    } else {
        int k = lane - NNZ_PER;
        s_c[w][1][k] = nstm[NNZ + row * NNZ_PER + k];
    }
    __syncthreads();

    float a0[8] = {0, 0, 0, 0, 0, 0, 0, 0};   // stm, features lane*8..lane*8+7
    float a1[8] = {0, 0, 0, 0, 0, 0, 0, 0};   // nstm

#pragma unroll 4
    for (int k = 0; k < NNZ_PER; k++) {
        float v = s_v[w][k];
        const uint4* p0 = (const uint4*)(Wt + (size_t)s_c[w][0][k] * FT_OUT);
        const uint4* p1 = (const uint4*)(Wt + (size_t)s_c[w][1][k] * FT_OUT);
        uint4 w0 = p0[lane];
        uint4 w1 = p1[lane];
        float e0, e1;
        unpack_bf16x2(w0.x, e0, e1); a0[0] += v * e0; a0[1] += v * e1;
        unpack_bf16x2(w0.y, e0, e1); a0[2] += v * e0; a0[3] += v * e1;
        unpack_bf16x2(w0.z, e0, e1); a0[4] += v * e0; a0[5] += v * e1;
        unpack_bf16x2(w0.w, e0, e1); a0[6] += v * e0; a0[7] += v * e1;
        unpack_bf16x2(w1.x, e0, e1); a1[0] += v * e0; a1[1] += v * e1;
        unpack_bf16x2(w1.y, e0, e1); a1[2] += v * e0; a1[3] += v * e1;
        unpack_bf16x2(w1.z, e0, e1); a1[4] += v * e0; a1[5] += v * e1;
        unpack_bf16x2(w1.w, e0, e1); a1[6] += v * e0; a1[7] += v * e1;
    }

    int ob = lane * 8;
    float bft[8], bff[8], wo0[8], wo1[8], fa0[8], fa1[8];
    *(float4*)&bft[0] = ((const float4*)(b_ft + ob))[0];
    *(float4*)&bft[4] = ((const float4*)(b_ft + ob))[1];
    *(float4*)&bff[0] = ((const float4*)(b_fft + ob))[0];
    *(float4*)&bff[4] = ((const float4*)(b_fft + ob))[1];
    *(float4*)&wo0[0] = ((const float4*)(W_out + ob))[0];
    *(float4*)&wo0[4] = ((const float4*)(W_out + ob))[1];
    *(float4*)&wo1[0] = ((const float4*)(W_out + FT_OUT + ob))[0];
    *(float4*)&wo1[4] = ((const float4*)(W_out + FT_OUT + ob))[1];
#pragma unroll
    for (int i = 0; i < 8; i++) { fa0[i] = 0.0f; fa1[i] = 0.0f; }
    if (row < MODV) {
#pragma unroll
        for (int ck = 0; ck < 4; ck++) {
            const float* p0 = fft_part + ((size_t)(ck * 2 + 0) * MODV + row) * FT_OUT + ob;
            const float* p1 = fft_part + ((size_t)(ck * 2 + 1) * MODV + row) * FT_OUT + ob;
            float t[8];
            *(float4*)&t[0] = ((const float4*)p0)[0];
            *(float4*)&t[4] = ((const float4*)p0)[1];
#pragma unroll
            for (int i = 0; i < 8; i++) fa0[i] += t[i];
            *(float4*)&t[0] = ((const float4*)p1)[0];
            *(float4*)&t[4] = ((const float4*)p1)[1];
#pragma unroll
            for (int i = 0; i < 8; i++) fa1[i] += t[i];
        }
    }

    float dot = 0.0f;
#pragma unroll
    for (int i = 0; i < 8; i++) {
        float h0 = clip01(a0[i] + bft[i] + bff[i] + fa0[i]);
        float h1 = clip01(a1[i] + bft[i] + bff[i] + fa1[i]);
        dot += h0 * wo0[i] + h1 * wo1[i];
    }

#pragma unroll
    for (int off = 32; off > 0; off >>= 1)
        dot += __shfl_down(dot, off, 64);

    if (lane == 0)
        out[row] = 1.0f / (1.0f + expf(-(dot + b_out[0])));
}

extern "C" void kernel_launch(void* const* d_in, const int* in_sizes, int n_in,
                              void* d_out, int out_size, void* d_ws, size_t ws_size,
                              hipStream_t stream) {
    const int*   stm   = (const int*)d_in[0];
    const int*   nstm  = (const int*)d_in[1];
    const float* vals  = (const float*)d_in[2];
    // d_in[3]: size scalar (compile-time B_SZ)
    const float* W_ft  = (const float*)d_in[4];
    const float* b_ft  = (const float*)d_in[5];
    const float* W_fft = (const float*)d_in[6];
    const float* b_fft = (const float*)d_in[7];
    const float* W_out = (const float*)d_in[8];
    const float* b_out = (const float*)d_in[9];
    float* out = (float*)d_out;

    unsigned short* Wt_bf = (unsigned short*)d_ws;                  // F_BIG*FT_OUT ushort
    float* Wfft_t   = (float*)(Wt_bf + (size_t)F_BIG * FT_OUT);     // MODV*FT_OUT
    float* H        = Wfft_t + (size_t)MODV * FT_OUT;               // 2*MODV*MODV
    float* fft_part = H + (size_t)2 * MODV * MODV;                  // 4*2*MODV*FT_OUT

    hipMemsetAsync(H, 0, (size_t)2 * MODV * MODV * sizeof(float), stream);

    prep_kernel<<<PREP_GRID, 256, 0, stream>>>(W_ft, W_fft, stm, nstm, vals,
                                               Wt_bf, Wfft_t, H);
    fft_gemm<<<640, 512, 0, stream>>>(H, Wfft_t, fft_part);
    main_kernel<<<B_SZ / 4, 256, 0, stream>>>(stm, nstm, vals, Wt_bf, b_ft, b_fft,
                                              fft_part, W_out, b_out, out);
}